// Round 1
// baseline (879.911 us; speedup 1.0000x reference)
//
#include <hip/hip_runtime.h>
#include <hip/hip_bf16.h>

typedef unsigned short u16;
typedef __attribute__((ext_vector_type(8))) __bf16 bf16x8;
typedef __attribute__((ext_vector_type(4))) float f32x4;

__device__ __forceinline__ u16 f2b(float f) {
  __hip_bfloat16 h = __float2bfloat16(f);
  u16 u;
  __builtin_memcpy(&u, &h, 2);
  return u;
}

__device__ __forceinline__ void gload16(const void* g, void* l) {
  __builtin_amdgcn_global_load_lds(
      (const __attribute__((address_space(1))) unsigned int*)g,
      (__attribute__((address_space(3))) unsigned int*)l, 16, 0, 0);
}

enum { OP_CONV_QK = 0, OP_CONV_V = 1, OP_SCORES = 2, OP_PV = 3, OP_HEAD1 = 4, OP_HEAD2 = 5 };

struct GP {
  const u16* A;
  const u16* Bt;
  int lda, ldb, K;
  long sAz, sBz;        // per-batch (blockIdx.z) element strides
  void* out;
  const float* bias;
  const float* gamma;   // device scalar
  const float* x_full;  // inputs base (fp32, row stride 2048)
  int x_off;            // PV: input col offset; HEAD2: output col offset
  const int* lens;
  const u16* zpage;
};

// 128x128 tile, BK=64, 4 waves, mfma_f32_16x16x32_bf16, NT (Bt row-major [n][k])
template <int TAG>
__global__ __launch_bounds__(256, 2) void gemm_k(GP p) {
  __shared__ __align__(16) u16 As[128][64];
  __shared__ __align__(16) u16 Bs[128][64];

  const int tid = threadIdx.x;
  const int lane = tid & 63;
  const int w = tid >> 6;
  const int wr = (w >> 1) * 64;   // wave row origin in tile
  const int wc = (w & 1) * 64;    // wave col origin in tile
  const int m0 = blockIdx.y * 128;
  const int n0 = blockIdx.x * 128;
  const int z = blockIdx.z;

  const u16* Ab = p.A + (long)z * p.sAz;
  const u16* Bb = p.Bt + (long)z * p.sBz;

  const int sr = tid >> 3;         // staging row within round (0..31)
  const int sc = (tid & 7) * 8;    // staging col (elements)

  f32x4 acc[4][4] = {};

  for (int k0 = 0; k0 < p.K; k0 += 64) {
    // ---- stage A tile (128x64 bf16, 4 rounds x 4KB) ----
#pragma unroll
    for (int R = 0; R < 4; ++R) {
      const int row = R * 32 + sr;
      const u16* src;
      if constexpr (TAG == OP_CONV_QK || TAG == OP_CONV_V) {
        // implicit im2col: k = dt*1024 + i  ->  xm[b, t+dt-1, i]
        const int m = m0 + row;
        const int b = m >> 9;
        const int t = (m & 511) + (k0 >> 10) - 1;
        const int ii = (k0 & 1023) + sc;
        src = ((unsigned)t < 512u) ? (Ab + ((((long)(b << 9)) + t) << 10) + ii)
                                   : p.zpage;
      } else {
        src = Ab + (long)(m0 + row) * p.lda + (k0 + sc);
      }
      gload16(src, (char*)(&As[0][0]) + R * 4096 + w * 1024);
    }
    // ---- stage B tile ----
#pragma unroll
    for (int R = 0; R < 4; ++R) {
      const int row = R * 32 + sr;
      const u16* src = Bb + (long)(n0 + row) * p.ldb + (k0 + sc);
      gload16(src, (char*)(&Bs[0][0]) + R * 4096 + w * 1024);
    }
    __syncthreads();
    // ---- MFMA on the 64-wide K slab ----
#pragma unroll
    for (int kk = 0; kk < 64; kk += 32) {
      const int kc = kk + (lane >> 4) * 8;
      bf16x8 aF[4], bF[4];
#pragma unroll
      for (int mi = 0; mi < 4; ++mi)
        aF[mi] = *(const bf16x8*)(&As[wr + mi * 16 + (lane & 15)][kc]);
#pragma unroll
      for (int ni = 0; ni < 4; ++ni)
        bF[ni] = *(const bf16x8*)(&Bs[wc + ni * 16 + (lane & 15)][kc]);
#pragma unroll
      for (int mi = 0; mi < 4; ++mi)
#pragma unroll
        for (int ni = 0; ni < 4; ++ni)
          acc[mi][ni] = __builtin_amdgcn_mfma_f32_16x16x32_bf16(
              aF[mi], bF[ni], acc[mi][ni], 0, 0, 0);
    }
    __syncthreads();
  }

  // ---- epilogue: C/D layout col=lane&15, row=(lane>>4)*4+j ----
  const int fr = (lane >> 4) * 4;
  const int fc = lane & 15;

  if constexpr (TAG == OP_CONV_QK) {
    u16* op = (u16*)p.out;
#pragma unroll
    for (int ni = 0; ni < 4; ++ni) {
      const int col = n0 + wc + ni * 16 + fc;
      const float bs = p.bias[col];
#pragma unroll
      for (int mi = 0; mi < 4; ++mi)
#pragma unroll
        for (int j = 0; j < 4; ++j) {
          const int row = m0 + wr + mi * 16 + fr + j;
          op[(long)row * 1024 + col] = f2b(acc[mi][ni][j] + bs);
        }
    }
  } else if constexpr (TAG == OP_CONV_V) {
    u16* op = (u16*)p.out;  // store transposed: v[b][chan][time]
#pragma unroll
    for (int ni = 0; ni < 4; ++ni) {
      const int col = n0 + wc + ni * 16 + fc;
      const float bs = p.bias[col];
#pragma unroll
      for (int mi = 0; mi < 4; ++mi)
#pragma unroll
        for (int j = 0; j < 4; ++j) {
          const int row = m0 + wr + mi * 16 + fr + j;
          const int b = row >> 9, t = row & 511;
          op[((long)b * 1024 + col) * 512 + t] = f2b(acc[mi][ni][j] + bs);
        }
    }
  } else if constexpr (TAG == OP_SCORES) {
    float* op = (float*)p.out + (long)z * 262144;
#pragma unroll
    for (int ni = 0; ni < 4; ++ni) {
      const int col = n0 + wc + ni * 16 + fc;
#pragma unroll
      for (int mi = 0; mi < 4; ++mi)
#pragma unroll
        for (int j = 0; j < 4; ++j) {
          const int row = m0 + wr + mi * 16 + fr + j;
          op[(long)row * 512 + col] = acc[mi][ni][j];
        }
    }
  } else if constexpr (TAG == OP_PV) {
    u16* op = (u16*)p.out + (long)z * 524288;
    const int len = p.lens[z];
    const float g = *p.gamma;
    const float* xb = p.x_full + (long)z * 512 * 2048 + p.x_off;
#pragma unroll
    for (int ni = 0; ni < 4; ++ni) {
      const int col = n0 + wc + ni * 16 + fc;
#pragma unroll
      for (int mi = 0; mi < 4; ++mi)
#pragma unroll
        for (int j = 0; j < 4; ++j) {
          const int row = m0 + wr + mi * 16 + fr + j;  // = t within batch
          const float xv = xb[(long)row * 2048 + col];
          const float r = (row < len) ? fmaf(g, acc[mi][ni][j], xv) : xv;
          op[(long)row * 1024 + col] = f2b(r);
        }
    }
  } else if constexpr (TAG == OP_HEAD1) {
    u16* op = (u16*)p.out;
#pragma unroll
    for (int ni = 0; ni < 4; ++ni) {
      const int col = n0 + wc + ni * 16 + fc;
      const float bs = p.bias[col];
#pragma unroll
      for (int mi = 0; mi < 4; ++mi)
#pragma unroll
        for (int j = 0; j < 4; ++j) {
          const int row = m0 + wr + mi * 16 + fr + j;
          op[(long)row * 1024 + col] = f2b(fmaxf(acc[mi][ni][j] + bs, 0.f));
        }
    }
  } else {  // OP_HEAD2: N=128, out fp32 row stride 256, col offset x_off
    float* op = (float*)p.out;
#pragma unroll
    for (int ni = 0; ni < 4; ++ni) {
      const int col = wc + ni * 16 + fc;  // n0 == 0
      const float bs = p.bias[col];
#pragma unroll
      for (int mi = 0; mi < 4; ++mi)
#pragma unroll
        for (int j = 0; j < 4; ++j) {
          const int row = m0 + wr + mi * 16 + fr + j;
          op[(long)row * 256 + p.x_off + col] = fmaxf(acc[mi][ni][j] + bs, 0.f);
        }
    }
  }
}

// one wave per row of 512 scores; ragged softmax with 1/sqrt(len) scale
__global__ __launch_bounds__(256) void softmax_k(const float* scores, u16* attn,
                                                 const int* lens) {
  const int row = blockIdx.x * 4 + (threadIdx.x >> 6);
  const int lane = threadIdx.x & 63;
  const int b = row >> 9;
  const int len = lens[b];
  const float inv = rsqrtf((float)len);
  const float* sr = scores + (long)row * 512;
  u16* ar = attn + (long)row * 512;
  float e[8];
  float mx = -1e30f;
#pragma unroll
  for (int j = 0; j < 8; ++j) {
    const int s = j * 64 + lane;
    const float v = (s < len) ? sr[s] * inv : -1e30f;
    e[j] = v;
    mx = fmaxf(mx, v);
  }
#pragma unroll
  for (int d = 1; d < 64; d <<= 1) mx = fmaxf(mx, __shfl_xor(mx, d));
  float sum = 0.f;
#pragma unroll
  for (int j = 0; j < 8; ++j) {
    const int s = j * 64 + lane;
    const float t = (s < len) ? __expf(e[j] - mx) : 0.f;
    e[j] = t;
    sum += t;
  }
#pragma unroll
  for (int d = 1; d < 64; d <<= 1) sum += __shfl_xor(sum, d);
  const float r = 1.f / sum;
#pragma unroll
  for (int j = 0; j < 8; ++j) {
    const int s = j * 64 + lane;
    ar[s] = f2b(e[j] * r);
  }
}

// conv weight (C,C,3) fp32 -> bf16 Bt layout [o][dt*1024+i]
__global__ void convw_k(const float* wsrc, u16* wt) {
  const int idx = blockIdx.x * 256 + threadIdx.x;  // o*1024+i
  const int o = idx >> 10, i = idx & 1023;
  const float* s = wsrc + (long)idx * 3;
  u16* d = wt + (long)o * 3072 + i;
  d[0] = f2b(s[0]);
  d[1024] = f2b(s[1]);
  d[2048] = f2b(s[2]);
}

__global__ void castk(const float* s, u16* d, int n) {
  const int i = blockIdx.x * 256 + threadIdx.x;
  if (i < n) d[i] = f2b(s[i]);
}

// masked bf16 copy of one half: xm[b,t,c] = t<len[b] ? x[b,t,off+c] : 0
__global__ void xmk(const float* inputs, u16* xm, const int* lens, int off) {
  const long idx = (long)blockIdx.x * 256 + threadIdx.x;  // 8192*1024
  const int row = (int)(idx >> 10), c = (int)(idx & 1023);
  const int b = row >> 9, t = row & 511;
  const float v = (t < lens[b]) ? inputs[(long)row * 2048 + off + c] : 0.f;
  xm[idx] = f2b(v);
}

__global__ void zerok(u16* p) { p[blockIdx.x * 256 + threadIdx.x] = 0; }

extern "C" void kernel_launch(void* const* d_in, const int* in_sizes, int n_in,
                              void* d_out, int out_size, void* d_ws, size_t ws_size,
                              hipStream_t stream) {
  const float* inputs = (const float*)d_in[0];
  const float* wq = (const float*)d_in[1];
  const float* bq = (const float*)d_in[2];
  const float* wk = (const float*)d_in[3];
  const float* bk = (const float*)d_in[4];
  const float* wv = (const float*)d_in[5];
  const float* bv = (const float*)d_in[6];
  const float* gamma = (const float*)d_in[7];
  const float* w_fcf = (const float*)d_in[8];
  const float* b_fcf = (const float*)d_in[9];
  const float* w_fc1f = (const float*)d_in[10];
  const float* b_fc1f = (const float*)d_in[11];
  const float* w_fcr = (const float*)d_in[12];
  const float* b_fcr = (const float*)d_in[13];
  const float* w_fc1r = (const float*)d_in[14];
  const float* b_fc1r = (const float*)d_in[15];
  const int* lens = (const int*)d_in[16];
  float* out = (float*)d_out;

  char* ws = (char*)d_ws;
  size_t off = 0;
  auto alloc = [&](size_t n) {
    char* p = ws + off;
    off += (n + 255) & ~(size_t)255;
    return p;
  };

  u16* wtq = (u16*)alloc(1024l * 3072 * 2);
  u16* wtk = (u16*)alloc(1024l * 3072 * 2);
  u16* wtv = (u16*)alloc(1024l * 3072 * 2);
  u16* w1f = (u16*)alloc(1024l * 1024 * 2);
  u16* w1r = (u16*)alloc(1024l * 1024 * 2);
  u16* w2f = (u16*)alloc(128l * 1024 * 2);
  u16* w2r = (u16*)alloc(128l * 1024 * 2);
  u16* xm = (u16*)alloc(8192l * 1024 * 2);
  u16* qb = (u16*)alloc(8192l * 1024 * 2);
  u16* kb = (u16*)alloc(8192l * 1024 * 2);
  u16* vbuf = (u16*)alloc(8192l * 1024 * 2);
  u16* abuf = (u16*)alloc(8192l * 1024 * 2);
  u16* hbuf = (u16*)alloc(8192l * 1024 * 2);
  float* scores = (float*)alloc(16l * 512 * 512 * 4);
  u16* attn = (u16*)alloc(16l * 512 * 512 * 2);
  u16* zpage = (u16*)alloc(4096);

  zerok<<<8, 256, 0, stream>>>(zpage);
  convw_k<<<4096, 256, 0, stream>>>(wq, wtq);
  convw_k<<<4096, 256, 0, stream>>>(wk, wtk);
  convw_k<<<4096, 256, 0, stream>>>(wv, wtv);
  castk<<<4096, 256, 0, stream>>>(w_fcf, w1f, 1024 * 1024);
  castk<<<4096, 256, 0, stream>>>(w_fcr, w1r, 1024 * 1024);
  castk<<<512, 256, 0, stream>>>(w_fc1f, w2f, 128 * 1024);
  castk<<<512, 256, 0, stream>>>(w_fc1r, w2r, 128 * 1024);

  for (int half = 0; half < 2; ++half) {
    const int xoff = (half == 0) ? 1024 : 0;     // f-half = cols 1024:, r-half = cols :1024
    const u16* w1 = (half == 0) ? w1f : w1r;
    const u16* w2 = (half == 0) ? w2f : w2r;
    const float* bh1 = (half == 0) ? b_fcf : b_fcr;
    const float* bh2 = (half == 0) ? b_fc1f : b_fc1r;
    const int ooff = (half == 0) ? 0 : 128;

    xmk<<<32768, 256, 0, stream>>>(inputs, xm, lens, xoff);

    GP g{};
    g.zpage = zpage;
    g.gamma = gamma;
    g.lens = lens;
    g.x_full = inputs;

    // conv q/k: natural [t][o] bf16 ; conv v: transposed [o][t]
    g.A = xm; g.lda = 1024; g.ldb = 3072; g.K = 3072;
    g.sAz = 0; g.sBz = 0; g.x_off = 0;
    g.Bt = wtq; g.out = qb; g.bias = bq;
    gemm_k<OP_CONV_QK><<<dim3(8, 64, 1), 256, 0, stream>>>(g);
    g.Bt = wtk; g.out = kb; g.bias = bk;
    gemm_k<OP_CONV_QK><<<dim3(8, 64, 1), 256, 0, stream>>>(g);
    g.Bt = wtv; g.out = vbuf; g.bias = bv;
    gemm_k<OP_CONV_V><<<dim3(8, 64, 1), 256, 0, stream>>>(g);

    // scores[t][s] = q . k  (per batch)
    g.A = qb; g.Bt = kb; g.lda = 1024; g.ldb = 1024; g.K = 1024;
    g.sAz = 512l * 1024; g.sBz = 512l * 1024; g.out = scores; g.bias = nullptr;
    gemm_k<OP_SCORES><<<dim3(4, 4, 16), 256, 0, stream>>>(g);

    softmax_k<<<2048, 256, 0, stream>>>(scores, attn, lens);

    // a[t][c] = mask ? gamma * (attn . v^T) + x : x
    g.A = attn; g.Bt = vbuf; g.lda = 512; g.ldb = 512; g.K = 512;
    g.sAz = 512l * 512; g.sBz = 1024l * 512; g.out = abuf; g.x_off = xoff;
    gemm_k<OP_PV><<<dim3(8, 4, 16), 256, 0, stream>>>(g);

    // head: h = relu(a @ w1^T + b1) ; y = relu(h @ w2^T + b2)
    g.A = abuf; g.Bt = w1; g.lda = 1024; g.ldb = 1024; g.K = 1024;
    g.sAz = 0; g.sBz = 0; g.out = hbuf; g.bias = bh1;
    gemm_k<OP_HEAD1><<<dim3(8, 64, 1), 256, 0, stream>>>(g);

    g.A = hbuf; g.Bt = w2; g.lda = 1024; g.ldb = 1024; g.K = 1024;
    g.out = out; g.bias = bh2; g.x_off = ooff;
    gemm_k<OP_HEAD2><<<dim3(1, 64, 1), 256, 0, stream>>>(g);
  }
}

// Round 2
// 705.566 us; speedup vs baseline: 1.2471x; 1.2471x over previous
//
#include <hip/hip_runtime.h>
#include <hip/hip_bf16.h>

typedef unsigned short u16;
typedef __attribute__((ext_vector_type(8))) __bf16 bf16x8;
typedef __attribute__((ext_vector_type(4))) float f32x4;

__device__ __forceinline__ u16 f2b(float f) {
  __hip_bfloat16 h = __float2bfloat16(f);
  u16 u;
  __builtin_memcpy(&u, &h, 2);
  return u;
}

__device__ __forceinline__ void gload16(const void* g, void* l) {
  __builtin_amdgcn_global_load_lds(
      (const __attribute__((address_space(1))) unsigned int*)g,
      (__attribute__((address_space(3))) unsigned int*)l, 16, 0, 0);
}

enum { OP_CONV = 0, OP_SCORES = 2, OP_PV = 3, OP_HEAD1 = 4, OP_HEAD2 = 5 };

struct GP {
  const u16* A;
  const u16* Bt;
  int lda, ldb, K, mbase;
  long sAz, sBz;         // per-z element strides
  void* out;
  void* out2;            // conv: kb
  void* out3;            // conv: vbuf (transposed)
  const float* bias;     // conv: bq / head: z==0 bias
  const float* bias2;    // conv: bk / head: z==1 bias
  const float* bias3;    // conv: bv
  const float* gamma;
  const float* x_full;   // original inputs (fp32, row stride 2048)
  const int* lens;
  const u16* zpage;
};

// 128x128 tile, BK=64, 4 waves, mfma_f32_16x16x32_bf16, NT (Bt row-major [n][k]).
// LDS tiles XOR-swizzled: slot_phys = slot_log ^ (row&7) (16B slots, 8/row).
// global_load_lds keeps a LINEAR lane-order dest; the swizzle is applied by
// permuting the per-lane GLOBAL source offset (rule: both-sides-or-neither).
template <int TAG>
__global__ __launch_bounds__(256, 4) void gemm_k(GP p) {
  __shared__ __align__(16) u16 As[128 * 64];
  __shared__ __align__(16) u16 Bs[128 * 64];

  const int tid = threadIdx.x;
  const int lane = tid & 63;
  const int w = tid >> 6;
  const int wr = (w >> 1) * 64;
  const int wc = (w & 1) * 64;
  const int m0 = blockIdx.y * 128;
  const int n0 = blockIdx.x * 128;
  const int z = blockIdx.z;

  const u16* Ab = p.A + (long)z * p.sAz;
  const u16* Bb = p.Bt + (long)z * p.sBz;

  const int sr = tid >> 3;                               // staging row (0..31 per round)
  const int scs = (((tid & 7) ^ ((tid >> 3) & 7)) << 3); // swizzled src element offset

  f32x4 acc[4][4] = {};

  for (int k0 = 0; k0 < p.K; k0 += 64) {
#pragma unroll
    for (int R = 0; R < 4; ++R) {
      const int row = R * 32 + sr;
      const u16* srcA;
      if constexpr (TAG == OP_CONV) {
        // implicit im2col: k = dt*1024 + i -> xm[b, t+dt-1, i] (half-local A)
        const int hrow = m0 + row;
        const int b = hrow >> 9;
        const int t = (hrow & 511) + (k0 >> 10) - 1;
        const int ii = (k0 & 1023) + scs;
        srcA = ((unsigned)t < 512u) ? (Ab + (((long)(b << 9) + t) << 10) + ii)
                                    : (p.zpage + scs);
      } else {
        srcA = Ab + (long)(m0 + row) * p.lda + (k0 + scs);
      }
      gload16(srcA, (char*)As + R * 4096 + w * 1024);
      const u16* srcB = Bb + (long)(n0 + row) * p.ldb + (k0 + scs);
      gload16(srcB, (char*)Bs + R * 4096 + w * 1024);
    }
    __syncthreads();
#pragma unroll
    for (int kk = 0; kk < 64; kk += 32) {
      const int kc = kk + (lane >> 4) * 8;
      const int slot = kc >> 3;
      bf16x8 aF[4], bF[4];
#pragma unroll
      for (int mi = 0; mi < 4; ++mi) {
        const int r = wr + mi * 16 + (lane & 15);
        aF[mi] = *(const bf16x8*)(As + r * 64 + ((slot ^ (r & 7)) << 3));
      }
#pragma unroll
      for (int ni = 0; ni < 4; ++ni) {
        const int r = wc + ni * 16 + (lane & 15);
        bF[ni] = *(const bf16x8*)(Bs + r * 64 + ((slot ^ (r & 7)) << 3));
      }
#pragma unroll
      for (int mi = 0; mi < 4; ++mi)
#pragma unroll
        for (int ni = 0; ni < 4; ++ni)
          acc[mi][ni] = __builtin_amdgcn_mfma_f32_16x16x32_bf16(
              aF[mi], bF[ni], acc[mi][ni], 0, 0, 0);
    }
    __syncthreads();
  }

  // C/D layout: col = lane&15, row = (lane>>4)*4 + j
  const int fr = (lane >> 4) * 4;
  const int fc = lane & 15;

  if constexpr (TAG == OP_CONV) {
    const int opid = n0 >> 10;  // 0=q 1=k 2=v (tile never crosses a 1024 boundary)
    const int nc = n0 & 1023;
    const float* bp = (opid == 0) ? p.bias : (opid == 1) ? p.bias2 : p.bias3;
#pragma unroll
    for (int ni = 0; ni < 4; ++ni) {
      const int col = nc + wc + ni * 16 + fc;
      const float bsv = bp[col];
#pragma unroll
      for (int mi = 0; mi < 4; ++mi)
#pragma unroll
        for (int j = 0; j < 4; ++j) {
          const int grow = p.mbase + m0 + wr + mi * 16 + fr + j;
          const u16 v = f2b(acc[mi][ni][j] + bsv);
          if (opid == 0) ((u16*)p.out)[(long)grow * 1024 + col] = v;
          else if (opid == 1) ((u16*)p.out2)[(long)grow * 1024 + col] = v;
          else ((u16*)p.out3)[((long)(grow >> 9) * 1024 + col) * 512 + (grow & 511)] = v;
        }
    }
  } else if constexpr (TAG == OP_SCORES) {
    float* op = (float*)p.out + (long)z * 262144;
#pragma unroll
    for (int ni = 0; ni < 4; ++ni) {
      const int col = n0 + wc + ni * 16 + fc;
#pragma unroll
      for (int mi = 0; mi < 4; ++mi)
#pragma unroll
        for (int j = 0; j < 4; ++j) {
          const int row = m0 + wr + mi * 16 + fr + j;
          op[(long)row * 512 + col] = acc[mi][ni][j];
        }
    }
  } else if constexpr (TAG == OP_PV) {
    u16* op = (u16*)p.out;
    const int half = z >> 4, b = z & 15;
    const int len = p.lens[b];
    const float g = *p.gamma;
    const float* xb = p.x_full + ((long)b * 512) * 2048 + (half == 0 ? 1024 : 0);
#pragma unroll
    for (int ni = 0; ni < 4; ++ni) {
      const int col = n0 + wc + ni * 16 + fc;
#pragma unroll
      for (int mi = 0; mi < 4; ++mi)
#pragma unroll
        for (int j = 0; j < 4; ++j) {
          const int t = m0 + wr + mi * 16 + fr + j;
          const float xv = xb[(long)t * 2048 + col];
          const float r = (t < len) ? fmaf(g, acc[mi][ni][j], xv) : xv;
          op[((long)z * 512 + t) * 1024 + col] = f2b(r);
        }
    }
  } else if constexpr (TAG == OP_HEAD1) {
    u16* op = (u16*)p.out;
    const float* bp = (z == 0) ? p.bias : p.bias2;
#pragma unroll
    for (int ni = 0; ni < 4; ++ni) {
      const int col = n0 + wc + ni * 16 + fc;
      const float bsv = bp[col];
#pragma unroll
      for (int mi = 0; mi < 4; ++mi)
#pragma unroll
        for (int j = 0; j < 4; ++j) {
          const int row = m0 + wr + mi * 16 + fr + j;
          op[((long)z * 8192 + row) * 1024 + col] = f2b(fmaxf(acc[mi][ni][j] + bsv, 0.f));
        }
    }
  } else {  // OP_HEAD2: N=128 (n0==0), fp32 out row stride 256, col block by z
    float* op = (float*)p.out;
    const float* bp = (z == 0) ? p.bias : p.bias2;
#pragma unroll
    for (int ni = 0; ni < 4; ++ni) {
      const int col = wc + ni * 16 + fc;
      const float bsv = bp[col];
#pragma unroll
      for (int mi = 0; mi < 4; ++mi)
#pragma unroll
        for (int j = 0; j < 4; ++j) {
          const int row = m0 + wr + mi * 16 + fr + j;
          op[(long)row * 256 + z * 128 + col] = fmaxf(acc[mi][ni][j] + bsv, 0.f);
        }
    }
  }
}

// one wave per row of 512 scores; ragged softmax with 1/sqrt(len) scale
__global__ __launch_bounds__(256) void softmax_k(const float* scores, u16* attn,
                                                 const int* lens) {
  const int row = blockIdx.x * 4 + (threadIdx.x >> 6);  // half-local row 0..8191
  const int lane = threadIdx.x & 63;
  const int len = lens[row >> 9];
  const float inv = rsqrtf((float)len);
  const float* sr = scores + (long)row * 512;
  u16* ar = attn + (long)row * 512;
  float e[8];
  float mx = -1e30f;
#pragma unroll
  for (int j = 0; j < 8; ++j) {
    const int s = j * 64 + lane;
    const float v = (s < len) ? sr[s] * inv : -1e30f;
    e[j] = v;
    mx = fmaxf(mx, v);
  }
#pragma unroll
  for (int d = 1; d < 64; d <<= 1) mx = fmaxf(mx, __shfl_xor(mx, d));
  float sum = 0.f;
#pragma unroll
  for (int j = 0; j < 8; ++j) {
    const int s = j * 64 + lane;
    const float t = (s < len) ? __expf(e[j] - mx) : 0.f;
    e[j] = t;
    sum += t;
  }
#pragma unroll
  for (int d = 1; d < 64; d <<= 1) sum += __shfl_xor(sum, d);
  const float r = 1.f / sum;
#pragma unroll
  for (int j = 0; j < 8; ++j) ar[j * 64 + lane] = f2b(e[j] * r);
}

// conv weight (C,C,3) fp32 -> bf16 Bt chunk [o][dt*1024+i]
__global__ void convw_k(const float* wsrc, u16* wt) {
  const int idx = blockIdx.x * 256 + threadIdx.x;  // o*1024+i
  const float* s = wsrc + (long)idx * 3;
  u16* d = wt + (long)(idx >> 10) * 3072 + (idx & 1023);
  d[0] = f2b(s[0]);
  d[1024] = f2b(s[1]);
  d[2048] = f2b(s[2]);
}

__global__ void castk(const float* s, u16* d, int n) {
  const int i = blockIdx.x * 256 + threadIdx.x;
  if (i < n) d[i] = f2b(s[i]);
}

// masked bf16 copy of one half (4 elems/thread): xm[row,c] = t<len ? x[row, off+c] : 0
__global__ void xmk(const float* inputs, u16* xm, const int* lens, int xoff) {
  const int idx = blockIdx.x * 256 + threadIdx.x;  // 8192*256
  const int row = idx >> 8;
  const int c4 = (idx & 255) * 4;
  const bool live = (row & 511) < lens[row >> 9];
  float4 v = {0.f, 0.f, 0.f, 0.f};
  if (live) v = *(const float4*)(inputs + (long)row * 2048 + xoff + c4);
  ushort4 o;
  o.x = f2b(v.x); o.y = f2b(v.y); o.z = f2b(v.z); o.w = f2b(v.w);
  *(ushort4*)(xm + (long)row * 1024 + c4) = o;
}

__global__ void zerok(u16* p) { p[blockIdx.x * 256 + threadIdx.x] = 0; }

extern "C" void kernel_launch(void* const* d_in, const int* in_sizes, int n_in,
                              void* d_out, int out_size, void* d_ws, size_t ws_size,
                              hipStream_t stream) {
  const float* inputs = (const float*)d_in[0];
  const float* wq = (const float*)d_in[1];
  const float* bq = (const float*)d_in[2];
  const float* wk = (const float*)d_in[3];
  const float* bk = (const float*)d_in[4];
  const float* wv = (const float*)d_in[5];
  const float* bv = (const float*)d_in[6];
  const float* gamma = (const float*)d_in[7];
  const float* w_fcf = (const float*)d_in[8];
  const float* b_fcf = (const float*)d_in[9];
  const float* w_fc1f = (const float*)d_in[10];
  const float* b_fc1f = (const float*)d_in[11];
  const float* w_fcr = (const float*)d_in[12];
  const float* b_fcr = (const float*)d_in[13];
  const float* w_fc1r = (const float*)d_in[14];
  const float* b_fc1r = (const float*)d_in[15];
  const int* lens = (const int*)d_in[16];
  float* out = (float*)d_out;

  char* ws = (char*)d_ws;
  size_t off = 0;
  auto alloc = [&](size_t n) {
    char* p = ws + off;
    off += (n + 255) & ~(size_t)255;
    return p;
  };

  // Aliasing plan (total ~141 MB, <= R1's proven footprint):
  //   wt_all (dead after conv)  -> attn (both halves)
  //   xm (per-half, dead after conv) -> scores fp32 (per-half)
  //   qb (dead after scores)    -> abuf
  //   kb (dead after scores)    -> hbuf
  u16* wt_all = (u16*)alloc(3072l * 3072 * 2);
  u16* w1b = (u16*)alloc(2l * 1024 * 1024 * 2);
  u16* w2b = (u16*)alloc(2l * 128 * 1024 * 2);
  u16* zpage = (u16*)alloc(4096);
  u16* xm = (u16*)alloc(8192l * 1024 * 2);
  u16* qb = (u16*)alloc(16384l * 1024 * 2);
  u16* kb = (u16*)alloc(16384l * 1024 * 2);
  u16* vb = (u16*)alloc(32l * 1024 * 512 * 2);
  u16* attn = wt_all;
  float* scores = (float*)xm;
  u16* abuf = qb;
  u16* hbuf = kb;

  zerok<<<8, 256, 0, stream>>>(zpage);
  convw_k<<<4096, 256, 0, stream>>>(wq, wt_all);
  convw_k<<<4096, 256, 0, stream>>>(wk, wt_all + 1024l * 3072);
  convw_k<<<4096, 256, 0, stream>>>(wv, wt_all + 2048l * 3072);
  castk<<<4096, 256, 0, stream>>>(w_fcf, w1b, 1024 * 1024);
  castk<<<4096, 256, 0, stream>>>(w_fcr, w1b + 1024l * 1024, 1024 * 1024);
  castk<<<512, 256, 0, stream>>>(w_fc1f, w2b, 128 * 1024);
  castk<<<512, 256, 0, stream>>>(w_fc1r, w2b + 128l * 1024, 128 * 1024);

  // fused q|k|v conv GEMM per half: M=8192, N=3072, K=3072 (1536 blocks)
  for (int half = 0; half < 2; ++half) {
    const int xoff = (half == 0) ? 1024 : 0;
    xmk<<<8192, 256, 0, stream>>>(inputs, xm, lens, xoff);
    GP g{};
    g.zpage = zpage;
    g.A = xm; g.Bt = wt_all; g.lda = 1024; g.ldb = 3072; g.K = 3072;
    g.mbase = half * 8192; g.sAz = 0; g.sBz = 0;
    g.out = qb; g.out2 = kb; g.out3 = vb;
    g.bias = bq; g.bias2 = bk; g.bias3 = bv;
    gemm_k<OP_CONV><<<dim3(24, 64, 1), 256, 0, stream>>>(g);
  }

  // scores + softmax per half (scores fp32 aliases xm)
  for (int half = 0; half < 2; ++half) {
    GP g{};
    g.A = qb + (long)half * 8192 * 1024;
    g.Bt = kb + (long)half * 8192 * 1024;
    g.lda = 1024; g.ldb = 1024; g.K = 1024;
    g.sAz = 512l * 1024; g.sBz = 512l * 1024;
    g.out = scores;
    gemm_k<OP_SCORES><<<dim3(4, 4, 16), 256, 0, stream>>>(g);
    softmax_k<<<2048, 256, 0, stream>>>(scores, attn + (long)half * 8192 * 512, lens);
  }

  // PV (z = half*16+b), both halves batched
  {
    GP g{};
    g.A = attn; g.Bt = vb; g.lda = 512; g.ldb = 512; g.K = 512;
    g.sAz = 512l * 512; g.sBz = 1024l * 512;
    g.out = abuf; g.gamma = gamma; g.x_full = inputs; g.lens = lens;
    gemm_k<OP_PV><<<dim3(8, 4, 32), 256, 0, stream>>>(g);
  }

  // head1 (z = half), both halves batched
  {
    GP g{};
    g.A = abuf; g.Bt = w1b; g.lda = 1024; g.ldb = 1024; g.K = 1024;
    g.sAz = 8192l * 1024; g.sBz = 1024l * 1024;
    g.out = hbuf; g.bias = b_fcf; g.bias2 = b_fcr;
    gemm_k<OP_HEAD1><<<dim3(8, 64, 2), 256, 0, stream>>>(g);
  }

  // head2 (z = half) -> strided concat store into d_out
  {
    GP g{};
    g.A = hbuf; g.Bt = w2b; g.lda = 1024; g.ldb = 1024; g.K = 1024;
    g.sAz = 8192l * 1024; g.sBz = 128l * 1024;
    g.out = out; g.bias = b_fc1f; g.bias2 = b_fc1r;
    gemm_k<OP_HEAD2><<<dim3(1, 64, 2), 256, 0, stream>>>(g);
  }
}

// Round 7
// 694.673 us; speedup vs baseline: 1.2667x; 1.0157x over previous
//
#include <hip/hip_runtime.h>
#include <hip/hip_bf16.h>

typedef unsigned short u16;
typedef __attribute__((ext_vector_type(8))) __bf16 bf16x8;
typedef __attribute__((ext_vector_type(4))) float f32x4;

__device__ __forceinline__ u16 f2b(float f) {
  __hip_bfloat16 h = __float2bfloat16(f);
  u16 u;
  __builtin_memcpy(&u, &h, 2);
  return u;
}

__device__ __forceinline__ void gload16(const void* g, void* l) {
  __builtin_amdgcn_global_load_lds(
      (const __attribute__((address_space(1))) unsigned int*)g,
      (__attribute__((address_space(3))) unsigned int*)l, 16, 0, 0);
}

// swizzled LDS fragment read: 16B slot = chunk ^ (row&7), row stride 128B
__device__ __forceinline__ bf16x8 ldsA(const char* base, int row, int ch) {
  return *(const bf16x8*)(base + row * 128 + ((ch ^ (row & 7)) << 4));
}

// ============================ 256x256 8-phase GEMM ============================
// TAG 0 = fused qkv conv (im2col, K=3072, N=3072), TAG 1 = head1 (K=1024,N=1024)
struct G2 {
  const u16* A;
  const u16* Bt;
  const u16* Bt2;   // head1: weights for rows >= 8192
  void* out;
  void* out2;       // conv: k
  void* out3;       // conv: v (transposed store)
  const float* bias;
  const float* bias2;
  const float* bias3;
  const u16* zpage;
  int K;
};

#define STAGE_A(kt, bi)                                                        \
  {                                                                            \
    _Pragma("unroll") for (int r_ = 0; r_ < 4; ++r_) {                         \
      const int idx_ = r_ * 512 + tid;                                         \
      const int row_ = idx_ >> 3;                                              \
      const int k_ = (kt) * 64 + (((idx_ & 7) ^ (row_ & 7)) << 3);             \
      const u16* src_;                                                         \
      if constexpr (TAG == 0) {                                                \
        const int gm_ = m0 + row_;                                             \
        const int t_ = (gm_ & 511) + (k_ >> 10) - 1;                           \
        src_ = ((unsigned)t_ < 512u)                                           \
                   ? p.A + ((((long)(gm_ >> 9) << 9) + t_) << 10) + (k_ & 1023)\
                   : p.zpage;                                                  \
      } else {                                                                 \
        src_ = p.A + (long)(m0 + row_) * 1024 + k_;                            \
      }                                                                        \
      gload16(src_, (char*)lds + (bi) * 65536 + r_ * 8192 + w * 1024);         \
    }                                                                          \
  }

#define STAGE_B(kt, bi)                                                        \
  {                                                                            \
    _Pragma("unroll") for (int r_ = 0; r_ < 4; ++r_) {                         \
      const int idx_ = r_ * 512 + tid;                                         \
      const int row_ = idx_ >> 3;                                              \
      const int k_ = (kt) * 64 + (((idx_ & 7) ^ (row_ & 7)) << 3);             \
      const u16* src_ = Bb + (long)(n0 + row_) * LDB + k_;                     \
      gload16(src_, (char*)lds + (bi) * 65536 + 32768 + r_ * 8192 + w * 1024); \
    }                                                                          \
  }

// one phase: frag ds_reads + optional B-frag load + stage-issue, raw barrier,
// prio-boosted 16-MFMA cluster. Caller adds the post-MFMA barrier.
#define PHASE(bi, qm, s, LOADB, STAGE_CODE)                                    \
  {                                                                            \
    const char* Ab_ = (const char*)lds + (bi) * 65536;                         \
    bf16x8 aF[4];                                                              \
    const int ch_ = (s) * 4 + (lane >> 4);                                     \
    const int r0_ = wr * 128 + (qm) * 64 + (lane & 15);                        \
    _Pragma("unroll") for (int fi = 0; fi < 4; ++fi)                           \
        aF[fi] = ldsA(Ab_, r0_ + fi * 16, ch_);                                \
    if (LOADB) {                                                               \
      const int rb_ = wc * 64 + (lane & 15);                                   \
      _Pragma("unroll") for (int ni = 0; ni < 4; ++ni)                         \
          bF[ni] = ldsA(Ab_ + 32768, rb_ + ni * 16, ch_);                      \
    }                                                                          \
    STAGE_CODE                                                                 \
    __builtin_amdgcn_s_barrier();                                              \
    __builtin_amdgcn_s_setprio(1);                                             \
    _Pragma("unroll") for (int fi = 0; fi < 4; ++fi)                           \
        _Pragma("unroll") for (int ni = 0; ni < 4; ++ni)                       \
            acc[(qm) * 4 + fi][ni] = __builtin_amdgcn_mfma_f32_16x16x32_bf16(  \
                aF[fi], bF[ni], acc[(qm) * 4 + fi][ni], 0, 0, 0);              \
    __builtin_amdgcn_s_setprio(0);                                             \
  }

template <int TAG>
__global__ __launch_bounds__(512, 2) void gemm256_k(G2 p) {
  __shared__ __align__(16) char lds[2 * 65536];  // [buf][A|B][256*64 u16]

  constexpr int NTN = (TAG == 0) ? 12 : 4;  // N / 256
  constexpr int LDB = (TAG == 0) ? 3072 : 1024;

  const int tid = threadIdx.x;
  const int lane = tid & 63;
  const int w = tid >> 6;
  const int wr = w >> 2;   // 0..1
  const int wc = w & 3;    // 0..3

  // bijective XCD swizzle (gridDim.x % 8 == 0)
  const int cpx = gridDim.x >> 3;
  const int wg = (blockIdx.x & 7) * cpx + (blockIdx.x >> 3);
  const int n0 = (wg % NTN) * 256;
  const int m0 = (wg / NTN) * 256;

  const u16* Bb = (TAG == 1 && m0 >= 8192) ? p.Bt2 : p.Bt;

  const int NT = p.K >> 6;

  f32x4 acc[8][4] = {};
  bf16x8 bF[4];

  // prologue: tile 0 -> buf 0
  STAGE_A(0, 0);
  STAGE_B(0, 0);
  asm volatile("s_waitcnt vmcnt(0)" ::: "memory");
  __builtin_amdgcn_s_barrier();

  for (int t = 0; t < NT; ++t) {
    const int bi = t & 1;
    const bool pf = (t + 1 < NT);
    PHASE(bi, 0, 0, true, { if (pf) STAGE_A(t + 1, bi ^ 1); });
    __builtin_amdgcn_s_barrier();
    PHASE(bi, 1, 0, false, { if (pf) STAGE_B(t + 1, bi ^ 1); });
    __builtin_amdgcn_s_barrier();
    PHASE(bi, 0, 1, true, {});
    __builtin_amdgcn_s_barrier();
    PHASE(bi, 1, 1, false, {});
    asm volatile("s_waitcnt vmcnt(0)" ::: "memory");  // tile t+1 landed (own loads)
    __builtin_amdgcn_s_barrier();                     // -> cross-wave visible
  }

  // epilogue: C/D col = lane&15, row = (lane>>4)*4 + j
  const int fr = (lane >> 4) * 4;
  const int fc = lane & 15;

  if constexpr (TAG == 0) {
    const int opid = n0 >> 10;  // 0=q 1=k 2=v (256-tiles never cross 1024)
    const int nc = n0 & 1023;
    const float* bp = (opid == 0) ? p.bias : (opid == 1) ? p.bias2 : p.bias3;
    u16* qo = (u16*)p.out;
    u16* ko = (u16*)p.out2;
    u16* vo = (u16*)p.out3;
#pragma unroll
    for (int ni = 0; ni < 4; ++ni) {
      const int col = nc + wc * 64 + ni * 16 + fc;
      const float bsv = bp[col];
#pragma unroll
      for (int mi = 0; mi < 8; ++mi)
#pragma unroll
        for (int j = 0; j < 4; ++j) {
          const int grow = m0 + wr * 128 + mi * 16 + fr + j;
          const u16 v = f2b(acc[mi][ni][j] + bsv);
          if (opid == 0) qo[(long)grow * 1024 + col] = v;
          else if (opid == 1) ko[(long)grow * 1024 + col] = v;
          else vo[((long)(grow >> 9) * 1024 + col) * 512 + (grow & 511)] = v;
        }
    }
  } else {
    const float* bp = (m0 >> 13) ? p.bias2 : p.bias;
    u16* ho = (u16*)p.out;
#pragma unroll
    for (int ni = 0; ni < 4; ++ni) {
      const int col = n0 + wc * 64 + ni * 16 + fc;
      const float bsv = bp[col];
#pragma unroll
      for (int mi = 0; mi < 8; ++mi)
#pragma unroll
        for (int j = 0; j < 4; ++j) {
          const int grow = m0 + wr * 128 + mi * 16 + fr + j;
          ho[(long)grow * 1024 + col] = f2b(fmaxf(acc[mi][ni][j] + bsv, 0.f));
        }
    }
  }
}

// ===================== 128x128 GEMM (proven R2 kernel) =======================
enum { OP_SCORES = 2, OP_PV = 3, OP_HEAD2 = 5 };

struct GP {
  const u16* A;
  const u16* Bt;
  int lda, ldb, K;
  long sAz, sBz;
  void* out;
  const float* bias;
  const float* bias2;
  const float* gamma;
  const float* x_full;
  const int* lens;
};

template <int TAG>
__global__ __launch_bounds__(256, 4) void gemm_k(GP p) {
  __shared__ __align__(16) u16 As[128 * 64];
  __shared__ __align__(16) u16 Bs[128 * 64];

  const int tid = threadIdx.x;
  const int lane = tid & 63;
  const int w = tid >> 6;
  const int wr = (w >> 1) * 64;
  const int wc = (w & 1) * 64;
  const int m0 = blockIdx.y * 128;
  const int n0 = blockIdx.x * 128;
  const int z = blockIdx.z;

  const u16* Ab = p.A + (long)z * p.sAz;
  const u16* Bb = p.Bt + (long)z * p.sBz;

  const int sr = tid >> 3;
  const int scs = (((tid & 7) ^ ((tid >> 3) & 7)) << 3);

  f32x4 acc[4][4] = {};

  for (int k0 = 0; k0 < p.K; k0 += 64) {
#pragma unroll
    for (int R = 0; R < 4; ++R) {
      const int row = R * 32 + sr;
      const u16* srcA = Ab + (long)(m0 + row) * p.lda + (k0 + scs);
      gload16(srcA, (char*)As + R * 4096 + w * 1024);
      const u16* srcB = Bb + (long)(n0 + row) * p.ldb + (k0 + scs);
      gload16(srcB, (char*)Bs + R * 4096 + w * 1024);
    }
    __syncthreads();
#pragma unroll
    for (int kk = 0; kk < 64; kk += 32) {
      const int slot = (kk >> 3) + (lane >> 4);
      bf16x8 aF[4], bF[4];
#pragma unroll
      for (int mi = 0; mi < 4; ++mi) {
        const int r = wr + mi * 16 + (lane & 15);
        aF[mi] = *(const bf16x8*)(As + r * 64 + ((slot ^ (r & 7)) << 3));
      }
#pragma unroll
      for (int ni = 0; ni < 4; ++ni) {
        const int r = wc + ni * 16 + (lane & 15);
        bF[ni] = *(const bf16x8*)(Bs + r * 64 + ((slot ^ (r & 7)) << 3));
      }
#pragma unroll
      for (int mi = 0; mi < 4; ++mi)
#pragma unroll
        for (int ni = 0; ni < 4; ++ni)
          acc[mi][ni] = __builtin_amdgcn_mfma_f32_16x16x32_bf16(
              aF[mi], bF[ni], acc[mi][ni], 0, 0, 0);
    }
    __syncthreads();
  }

  const int fr = (lane >> 4) * 4;
  const int fc = lane & 15;

  if constexpr (TAG == OP_SCORES) {
    float* op = (float*)p.out + (long)z * 262144;
#pragma unroll
    for (int ni = 0; ni < 4; ++ni) {
      const int col = n0 + wc + ni * 16 + fc;
#pragma unroll
      for (int mi = 0; mi < 4; ++mi)
#pragma unroll
        for (int j = 0; j < 4; ++j) {
          const int row = m0 + wr + mi * 16 + fr + j;
          op[(long)row * 512 + col] = acc[mi][ni][j];
        }
    }
  } else if constexpr (TAG == OP_PV) {
    u16* op = (u16*)p.out;
    const int half = z >> 4, b = z & 15;
    const int len = p.lens[b];
    const float g = *p.gamma;
    const float* xb = p.x_full + ((long)b * 512) * 2048 + (half == 0 ? 1024 : 0);
#pragma unroll
    for (int ni = 0; ni < 4; ++ni) {
      const int col = n0 + wc + ni * 16 + fc;
#pragma unroll
      for (int mi = 0; mi < 4; ++mi)
#pragma unroll
        for (int j = 0; j < 4; ++j) {
          const int t = m0 + wr + mi * 16 + fr + j;
          const float xv = xb[(long)t * 2048 + col];
          const float r = (t < len) ? fmaf(g, acc[mi][ni][j], xv) : xv;
          op[((long)z * 512 + t) * 1024 + col] = f2b(r);
        }
    }
  } else {  // OP_HEAD2
    float* op = (float*)p.out;
    const float* bp = (z == 0) ? p.bias : p.bias2;
#pragma unroll
    for (int ni = 0; ni < 4; ++ni) {
      const int col = wc + ni * 16 + fc;
      const float bsv = bp[col];
#pragma unroll
      for (int mi = 0; mi < 4; ++mi)
#pragma unroll
        for (int j = 0; j < 4; ++j) {
          const int row = m0 + wr + mi * 16 + fr + j;
          op[(long)row * 256 + z * 128 + col] = fmaxf(acc[mi][ni][j] + bsv, 0.f);
        }
    }
  }
}

// ============================= small kernels =================================
__global__ __launch_bounds__(256) void softmax_k(const float* scores, u16* attn,
                                                 const int* lens) {
  const int row = blockIdx.x * 4 + (threadIdx.x >> 6);  // 0..16383
  const int lane = threadIdx.x & 63;
  const int len = lens[(row >> 9) & 15];
  const float inv = rsqrtf((float)len);
  const float* sr = scores + (long)row * 512;
  u16* ar = attn + (long)row * 512;
  float e[8];
  float mx = -1e30f;
#pragma unroll
  for (int j = 0; j < 8; ++j) {
    const int s = j * 64 + lane;
    const float v = (s < len) ? sr[s] * inv : -1e30f;
    e[j] = v;
    mx = fmaxf(mx, v);
  }
#pragma unroll
  for (int d = 1; d < 64; d <<= 1) mx = fmaxf(mx, __shfl_xor(mx, d));
  float sum = 0.f;
#pragma unroll
  for (int j = 0; j < 8; ++j) {
    const int s = j * 64 + lane;
    const float t = (s < len) ? __expf(e[j] - mx) : 0.f;
    e[j] = t;
    sum += t;
  }
#pragma unroll
  for (int d = 1; d < 64; d <<= 1) sum += __shfl_xor(sum, d);
  const float r = 1.f / sum;
#pragma unroll
  for (int j = 0; j < 8; ++j) ar[j * 64 + lane] = f2b(e[j] * r);
}

__global__ void convw_k(const float* wsrc, u16* wt) {
  const int idx = blockIdx.x * 256 + threadIdx.x;  // o*1024+i
  const float* s = wsrc + (long)idx * 3;
  u16* d = wt + (long)(idx >> 10) * 3072 + (idx & 1023);
  d[0] = f2b(s[0]);
  d[1024] = f2b(s[1]);
  d[2048] = f2b(s[2]);
}

__global__ void castk(const float* s, u16* d, int n) {
  const int i = blockIdx.x * 256 + threadIdx.x;
  if (i < n) d[i] = f2b(s[i]);
}

// masked bf16 copy, both halves: rows 0-8191 = f (cols 1024:), 8192.. = r (:1024)
__global__ void xmk(const float* inputs, u16* xm, const int* lens) {
  const int idx = blockIdx.x * 256 + threadIdx.x;  // 16384*256
  const int row = idx >> 8;
  const int c4 = (idx & 255) * 4;
  const int xoff = (row & 8192) ? 0 : 1024;
  const bool live = (row & 511) < lens[(row >> 9) & 15];
  float4 v = {0.f, 0.f, 0.f, 0.f};
  if (live) v = *(const float4*)(inputs + (long)(row & 8191) * 2048 + xoff + c4);
  ushort4 o;
  o.x = f2b(v.x); o.y = f2b(v.y); o.z = f2b(v.z); o.w = f2b(v.w);
  *(ushort4*)(xm + (long)row * 1024 + c4) = o;
}

__global__ void zerok(u16* p) { p[blockIdx.x * 256 + threadIdx.x] = 0; }

extern "C" void kernel_launch(void* const* d_in, const int* in_sizes, int n_in,
                              void* d_out, int out_size, void* d_ws, size_t ws_size,
                              hipStream_t stream) {
  const float* inputs = (const float*)d_in[0];
  const float* wq = (const float*)d_in[1];
  const float* bq = (const float*)d_in[2];
  const float* wk = (const float*)d_in[3];
  const float* bk = (const float*)d_in[4];
  const float* wv = (const float*)d_in[5];
  const float* bv = (const float*)d_in[6];
  const float* gamma = (const float*)d_in[7];
  const float* w_fcf = (const float*)d_in[8];
  const float* b_fcf = (const float*)d_in[9];
  const float* w_fc1f = (const float*)d_in[10];
  const float* b_fc1f = (const float*)d_in[11];
  const float* w_fcr = (const float*)d_in[12];
  const float* b_fcr = (const float*)d_in[13];
  const float* w_fc1r = (const float*)d_in[14];
  const float* b_fc1r = (const float*)d_in[15];
  const int* lens = (const int*)d_in[16];
  float* out = (float*)d_out;

  char* ws = (char*)d_ws;
  size_t off = 0;
  auto alloc = [&](size_t n) {
    char* p = ws + off;
    off += (n + 255) & ~(size_t)255;
    return p;
  };

  // Live-set peak (conv): wt_all + xm + qb + kb + vb = 153.1 MB.
  // Aliases: attn->wt_all (post-conv); scores fp32->xm (post-conv);
  // w1b/w2b->xm region (post-softmax); abuf->qb; hbuf->kb.
  u16* wt_all = (u16*)alloc(3072l * 3072 * 2);
  u16* zpage = (u16*)alloc(4096);
  u16* xm = (u16*)alloc(16384l * 1024 * 2);
  u16* qb = (u16*)alloc(16384l * 1024 * 2);
  u16* kb = (u16*)alloc(16384l * 1024 * 2);
  u16* vb = (u16*)alloc(32l * 1024 * 512 * 2);
  u16* attn = wt_all;
  float* scores = (float*)xm;
  u16* w1b = (u16*)xm;                    // after softmax (scores dead)
  u16* w2b = w1b + 2l * 1024 * 1024;
  u16* abuf = qb;
  u16* hbuf = kb;

  zerok<<<8, 256, 0, stream>>>(zpage);
  convw_k<<<4096, 256, 0, stream>>>(wq, wt_all);
  convw_k<<<4096, 256, 0, stream>>>(wk, wt_all + 1024l * 3072);
  convw_k<<<4096, 256, 0, stream>>>(wv, wt_all + 2048l * 3072);
  xmk<<<16384, 256, 0, stream>>>(inputs, xm, lens);

  // fused q|k|v conv: M=16384, N=3072, K=3072 -> 768 blocks (3 full rounds)
  {
    G2 g{};
    g.A = xm; g.Bt = wt_all; g.zpage = zpage; g.K = 3072;
    g.out = qb; g.out2 = kb; g.out3 = vb;
    g.bias = bq; g.bias2 = bk; g.bias3 = bv;
    gemm256_k<0><<<768, 512, 0, stream>>>(g);
  }

  // scores, both halves batched (z = half*16 + b); scores fp32 aliases xm
  {
    GP g{};
    g.A = qb; g.Bt = kb; g.lda = 1024; g.ldb = 1024; g.K = 1024;
    g.sAz = 512l * 1024; g.sBz = 512l * 1024; g.out = scores;
    gemm_k<OP_SCORES><<<dim3(4, 4, 32), 256, 0, stream>>>(g);
  }
  softmax_k<<<4096, 256, 0, stream>>>(scores, attn, lens);

  // head weights -> bf16 into the (now dead) scores region
  castk<<<4096, 256, 0, stream>>>(w_fcf, w1b, 1024 * 1024);
  castk<<<4096, 256, 0, stream>>>(w_fcr, w1b + 1024l * 1024, 1024 * 1024);
  castk<<<512, 256, 0, stream>>>(w_fc1f, w2b, 128 * 1024);
  castk<<<512, 256, 0, stream>>>(w_fc1r, w2b + 128l * 1024, 128 * 1024);

  // PV: a = mask ? gamma*(attn.vT)+x : x  (z = half*16+b)
  {
    GP g{};
    g.A = attn; g.Bt = vb; g.lda = 512; g.ldb = 512; g.K = 512;
    g.sAz = 512l * 512; g.sBz = 1024l * 512;
    g.out = abuf; g.gamma = gamma; g.x_full = inputs; g.lens = lens;
    gemm_k<OP_PV><<<dim3(8, 4, 32), 256, 0, stream>>>(g);
  }

  // head1: M=16384, N=1024, K=1024 -> 256 blocks (1 full round)
  {
    G2 h{};
    h.A = abuf; h.Bt = w1b; h.Bt2 = w1b + 1024l * 1024; h.K = 1024;
    h.out = hbuf; h.bias = b_fcf; h.bias2 = b_fcr;
    gemm256_k<1><<<256, 512, 0, stream>>>(h);
  }

  // head2 -> strided concat store into d_out
  {
    GP g{};
    g.A = hbuf; g.Bt = w2b; g.lda = 1024; g.ldb = 1024; g.K = 1024;
    g.sAz = 8192l * 1024; g.sBz = 128l * 1024;
    g.out = out; g.bias = b_fc1f; g.bias2 = b_fc1r;
    gemm_k<OP_HEAD2><<<dim3(1, 64, 2), 256, 0, stream>>>(g);
  }
}

// Round 8
// 678.464 us; speedup vs baseline: 1.2969x; 1.0239x over previous
//
#include <hip/hip_runtime.h>
#include <hip/hip_bf16.h>

typedef unsigned short u16;
typedef __attribute__((ext_vector_type(8))) __bf16 bf16x8;
typedef __attribute__((ext_vector_type(4))) float f32x4;

__device__ __forceinline__ u16 f2b(float f) {
  __hip_bfloat16 h = __float2bfloat16(f);
  u16 u;
  __builtin_memcpy(&u, &h, 2);
  return u;
}

__device__ __forceinline__ void gload16(const void* g, void* l) {
  __builtin_amdgcn_global_load_lds(
      (const __attribute__((address_space(1))) unsigned int*)g,
      (__attribute__((address_space(3))) unsigned int*)l, 16, 0, 0);
}

// [256][32] bf16 tile, 64B rows = 4 x 16B slots; slot = ch ^ ((row>>1)&3)
// -> 64 lanes of a frag-read spread over all 32 banks (2-way, free).
__device__ __forceinline__ bf16x8 ldsF(const char* base, int row, int ch) {
  return *(const bf16x8*)(base + row * 64 + ((ch ^ ((row >> 1) & 3)) << 4));
}

// ================= 256x256 GEMM, BK=32, 4-deep counted-vmcnt pipeline ========
// TAG 0 = fused qkv conv (im2col, K=3072, N=3072), TAG 1 = head1 (K=1024,N=1024)
struct G2 {
  const u16* A;
  const u16* Bt;
  const u16* Bt2;   // head1: weights for rows >= 8192
  void* out;
  void* out2;       // conv: k
  void* out3;       // conv: v (transposed store)
  const float* bias;
  const float* bias2;
  const float* bias3;
  const u16* zpage;
  int K;
};

// stage K-tile kt into buffer bi: A[256][32] + B[256][32], 4 gload16/thread.
// global source chunk pre-swizzled to match ldsF's read XOR (rule 21).
#define STG(kt, bi)                                                            \
  {                                                                            \
    _Pragma("unroll") for (int r_ = 0; r_ < 2; ++r_) {                         \
      const int idx_ = r_ * 512 + tid;                                         \
      const int row_ = idx_ >> 2;                                              \
      const int k_ = (kt) * 32 + (((idx_ & 3) ^ ((row_ >> 1) & 3)) << 3);      \
      const u16* src_;                                                         \
      if constexpr (TAG == 0) {                                                \
        const int gm_ = m0 + row_;                                             \
        const int t_ = (gm_ & 511) + (k_ >> 10) - 1;                           \
        src_ = ((unsigned)t_ < 512u)                                           \
                   ? p.A + ((((long)(gm_ >> 9) << 9) + t_) << 10) + (k_ & 1023)\
                   : p.zpage;                                                  \
      } else {                                                                 \
        src_ = p.A + (long)(m0 + row_) * 1024 + k_;                            \
      }                                                                        \
      gload16(src_, (char*)lds + (bi) * 32768 + r_ * 8192 + w * 1024);         \
    }                                                                          \
    _Pragma("unroll") for (int r_ = 0; r_ < 2; ++r_) {                         \
      const int idx_ = r_ * 512 + tid;                                         \
      const int row_ = idx_ >> 2;                                              \
      const int k_ = (kt) * 32 + (((idx_ & 3) ^ ((row_ >> 1) & 3)) << 3);      \
      const u16* src_ = Bb + (long)(n0 + row_) * LDB + k_;                     \
      gload16(src_, (char*)lds + (bi) * 32768 + 16384 + r_ * 8192 + w * 1024); \
    }                                                                          \
  }

// compute one K-tile (K=32) from buffer bi: 12 ds_read_b128 + 32 MFMA
#define CMP(bi)                                                                \
  {                                                                            \
    const char* Ab_ = (const char*)lds + (bi) * 32768;                         \
    bf16x8 aF[8], bF[4];                                                       \
    const int ch_ = lane >> 4;                                                 \
    const int rA_ = wr * 128 + (lane & 15);                                    \
    const int rB_ = wc * 64 + (lane & 15);                                     \
    _Pragma("unroll") for (int mi = 0; mi < 8; ++mi)                           \
        aF[mi] = ldsF(Ab_, rA_ + mi * 16, ch_);                                \
    _Pragma("unroll") for (int ni = 0; ni < 4; ++ni)                           \
        bF[ni] = ldsF(Ab_ + 16384, rB_ + ni * 16, ch_);                        \
    __builtin_amdgcn_s_setprio(1);                                             \
    _Pragma("unroll") for (int mi = 0; mi < 8; ++mi)                           \
        _Pragma("unroll") for (int ni = 0; ni < 4; ++ni)                       \
            acc[mi][ni] = __builtin_amdgcn_mfma_f32_16x16x32_bf16(             \
                aF[mi], bF[ni], acc[mi][ni], 0, 0, 0);                         \
    __builtin_amdgcn_s_setprio(0);                                             \
  }

template <int TAG>
__global__ __launch_bounds__(512, 2) void gemm256_k(G2 p) {
  __shared__ __align__(16) char lds[4 * 32768];  // 4 K-tile buffers (A|B)

  constexpr int NTN = (TAG == 0) ? 12 : 4;  // N / 256
  constexpr int LDB = (TAG == 0) ? 3072 : 1024;

  const int tid = threadIdx.x;
  const int lane = tid & 63;
  const int w = tid >> 6;
  const int wr = w >> 2;   // 0..1
  const int wc = w & 3;    // 0..3

  // bijective XCD swizzle (gridDim.x % 8 == 0)
  const int cpx = gridDim.x >> 3;
  const int wg = (blockIdx.x & 7) * cpx + (blockIdx.x >> 3);
  const int n0 = (wg % NTN) * 256;
  const int m0 = (wg / NTN) * 256;

  const u16* Bb = (TAG == 1 && m0 >= 8192) ? p.Bt2 : p.Bt;

  const int NT = p.K >> 5;  // K-tiles of 32

  f32x4 acc[8][4] = {};

  // prologue: 3 tiles in flight, publish tile 0 (own loads ≤8 -> T0 landed)
  STG(0, 0);
  STG(1, 1);
  STG(2, 2);
  asm volatile("s_waitcnt vmcnt(8)" ::: "memory");
  __builtin_amdgcn_s_barrier();

  int t = 0;
  for (; t < NT - 3; ++t) {
    STG(t + 3, (t + 3) & 3);   // buffer (t+3)&3 died at iter t-1
    CMP(t & 3);
    // counted wait: all but newest 8 loads (tiles t+2,t+3) done -> t+1 landed
    asm volatile("s_waitcnt vmcnt(8)" ::: "memory");
    __builtin_amdgcn_s_barrier();
  }
  // epilogue: drain 8 -> 4 -> 0, no new stages
  CMP(t & 3);
  asm volatile("s_waitcnt vmcnt(4)" ::: "memory");
  __builtin_amdgcn_s_barrier();
  ++t;
  CMP(t & 3);
  asm volatile("s_waitcnt vmcnt(0)" ::: "memory");
  __builtin_amdgcn_s_barrier();
  ++t;
  CMP(t & 3);

  // epilogue: C/D col = lane&15, row = (lane>>4)*4 + j ; acc row = wr*128+mi*16
  const int fr = (lane >> 4) * 4;
  const int fc = lane & 15;

  if constexpr (TAG == 0) {
    const int opid = n0 >> 10;  // 0=q 1=k 2=v (256-tiles never cross 1024)
    const int nc = n0 & 1023;
    const float* bp = (opid == 0) ? p.bias : (opid == 1) ? p.bias2 : p.bias3;
    u16* qo = (u16*)p.out;
    u16* ko = (u16*)p.out2;
    u16* vo = (u16*)p.out3;
#pragma unroll
    for (int ni = 0; ni < 4; ++ni) {
      const int col = nc + wc * 64 + ni * 16 + fc;
      const float bsv = bp[col];
#pragma unroll
      for (int mi = 0; mi < 8; ++mi)
#pragma unroll
        for (int j = 0; j < 4; ++j) {
          const int grow = m0 + wr * 128 + mi * 16 + fr + j;
          const u16 v = f2b(acc[mi][ni][j] + bsv);
          if (opid == 0) qo[(long)grow * 1024 + col] = v;
          else if (opid == 1) ko[(long)grow * 1024 + col] = v;
          else vo[((long)(grow >> 9) * 1024 + col) * 512 + (grow & 511)] = v;
        }
    }
  } else {
    const float* bp = (m0 >> 13) ? p.bias2 : p.bias;
    u16* ho = (u16*)p.out;
#pragma unroll
    for (int ni = 0; ni < 4; ++ni) {
      const int col = n0 + wc * 64 + ni * 16 + fc;
      const float bsv = bp[col];
#pragma unroll
      for (int mi = 0; mi < 8; ++mi)
#pragma unroll
        for (int j = 0; j < 4; ++j) {
          const int grow = m0 + wr * 128 + mi * 16 + fr + j;
          ho[(long)grow * 1024 + col] = f2b(fmaxf(acc[mi][ni][j] + bsv, 0.f));
        }
    }
  }
}

// ===================== 128x128 GEMM (proven R2 kernel) =======================
enum { OP_SCORES = 2, OP_PV = 3, OP_HEAD2 = 5 };

struct GP {
  const u16* A;
  const u16* Bt;
  int lda, ldb, K;
  long sAz, sBz;
  void* out;
  const float* bias;
  const float* bias2;
  const float* gamma;
  const float* x_full;
  const int* lens;
};

template <int TAG>
__global__ __launch_bounds__(256, 4) void gemm_k(GP p) {
  __shared__ __align__(16) u16 As[128 * 64];
  __shared__ __align__(16) u16 Bs[128 * 64];

  const int tid = threadIdx.x;
  const int lane = tid & 63;
  const int w = tid >> 6;
  const int wr = (w >> 1) * 64;
  const int wc = (w & 1) * 64;
  const int m0 = blockIdx.y * 128;
  const int n0 = blockIdx.x * 128;
  const int z = blockIdx.z;

  const u16* Ab = p.A + (long)z * p.sAz;
  const u16* Bb = p.Bt + (long)z * p.sBz;

  const int sr = tid >> 3;
  const int scs = (((tid & 7) ^ ((tid >> 3) & 7)) << 3);

  f32x4 acc[4][4] = {};

  for (int k0 = 0; k0 < p.K; k0 += 64) {
#pragma unroll
    for (int R = 0; R < 4; ++R) {
      const int row = R * 32 + sr;
      const u16* srcA = Ab + (long)(m0 + row) * p.lda + (k0 + scs);
      gload16(srcA, (char*)As + R * 4096 + w * 1024);
      const u16* srcB = Bb + (long)(n0 + row) * p.ldb + (k0 + scs);
      gload16(srcB, (char*)Bs + R * 4096 + w * 1024);
    }
    __syncthreads();
#pragma unroll
    for (int kk = 0; kk < 64; kk += 32) {
      const int slot = (kk >> 3) + (lane >> 4);
      bf16x8 aF[4], bF[4];
#pragma unroll
      for (int mi = 0; mi < 4; ++mi) {
        const int r = wr + mi * 16 + (lane & 15);
        aF[mi] = *(const bf16x8*)(As + r * 64 + ((slot ^ (r & 7)) << 3));
      }
#pragma unroll
      for (int ni = 0; ni < 4; ++ni) {
        const int r = wc + ni * 16 + (lane & 15);
        bF[ni] = *(const bf16x8*)(Bs + r * 64 + ((slot ^ (r & 7)) << 3));
      }
#pragma unroll
      for (int mi = 0; mi < 4; ++mi)
#pragma unroll
        for (int ni = 0; ni < 4; ++ni)
          acc[mi][ni] = __builtin_amdgcn_mfma_f32_16x16x32_bf16(
              aF[mi], bF[ni], acc[mi][ni], 0, 0, 0);
    }
    __syncthreads();
  }

  const int fr = (lane >> 4) * 4;
  const int fc = lane & 15;

  if constexpr (TAG == OP_SCORES) {
    float* op = (float*)p.out + (long)z * 262144;
#pragma unroll
    for (int ni = 0; ni < 4; ++ni) {
      const int col = n0 + wc + ni * 16 + fc;
#pragma unroll
      for (int mi = 0; mi < 4; ++mi)
#pragma unroll
        for (int j = 0; j < 4; ++j) {
          const int row = m0 + wr + mi * 16 + fr + j;
          op[(long)row * 512 + col] = acc[mi][ni][j];
        }
    }
  } else if constexpr (TAG == OP_PV) {
    u16* op = (u16*)p.out;
    const int half = z >> 4, b = z & 15;
    const int len = p.lens[b];
    const float g = *p.gamma;
    const float* xb = p.x_full + ((long)b * 512) * 2048 + (half == 0 ? 1024 : 0);
#pragma unroll
    for (int ni = 0; ni < 4; ++ni) {
      const int col = n0 + wc + ni * 16 + fc;
#pragma unroll
      for (int mi = 0; mi < 4; ++mi)
#pragma unroll
        for (int j = 0; j < 4; ++j) {
          const int t = m0 + wr + mi * 16 + fr + j;
          const float xv = xb[(long)t * 2048 + col];
          const float r = (t < len) ? fmaf(g, acc[mi][ni][j], xv) : xv;
          op[((long)z * 512 + t) * 1024 + col] = f2b(r);
        }
    }
  } else {  // OP_HEAD2
    float* op = (float*)p.out;
    const float* bp = (z == 0) ? p.bias : p.bias2;
#pragma unroll
    for (int ni = 0; ni < 4; ++ni) {
      const int col = wc + ni * 16 + fc;
      const float bsv = bp[col];
#pragma unroll
      for (int mi = 0; mi < 4; ++mi)
#pragma unroll
        for (int j = 0; j < 4; ++j) {
          const int row = m0 + wr + mi * 16 + fr + j;
          op[(long)row * 256 + z * 128 + col] = fmaxf(acc[mi][ni][j] + bsv, 0.f);
        }
    }
  }
}

// ============================= small kernels =================================
__global__ __launch_bounds__(256) void softmax_k(const float* scores, u16* attn,
                                                 const int* lens) {
  const int row = blockIdx.x * 4 + (threadIdx.x >> 6);  // 0..16383
  const int lane = threadIdx.x & 63;
  const int len = lens[(row >> 9) & 15];
  const float inv = rsqrtf((float)len);
  const float* sr = scores + (long)row * 512;
  u16* ar = attn + (long)row * 512;
  float e[8];
  float mx = -1e30f;
#pragma unroll
  for (int j = 0; j < 8; ++j) {
    const int s = j * 64 + lane;
    const float v = (s < len) ? sr[s] * inv : -1e30f;
    e[j] = v;
    mx = fmaxf(mx, v);
  }
#pragma unroll
  for (int d = 1; d < 64; d <<= 1) mx = fmaxf(mx, __shfl_xor(mx, d));
  float sum = 0.f;
#pragma unroll
  for (int j = 0; j < 8; ++j) {
    const int s = j * 64 + lane;
    const float t = (s < len) ? __expf(e[j] - mx) : 0.f;
    e[j] = t;
    sum += t;
  }
#pragma unroll
  for (int d = 1; d < 64; d <<= 1) sum += __shfl_xor(sum, d);
  const float r = 1.f / sum;
#pragma unroll
  for (int j = 0; j < 8; ++j) ar[j * 64 + lane] = f2b(e[j] * r);
}

__global__ void convw_k(const float* wsrc, u16* wt) {
  const int idx = blockIdx.x * 256 + threadIdx.x;  // o*1024+i
  const float* s = wsrc + (long)idx * 3;
  u16* d = wt + (long)(idx >> 10) * 3072 + (idx & 1023);
  d[0] = f2b(s[0]);
  d[1024] = f2b(s[1]);
  d[2048] = f2b(s[2]);
}

__global__ void castk(const float* s, u16* d, int n) {
  const int i = blockIdx.x * 256 + threadIdx.x;
  if (i < n) d[i] = f2b(s[i]);
}

// masked bf16 copy, both halves: rows 0-8191 = f (cols 1024:), 8192.. = r (:1024)
__global__ void xmk(const float* inputs, u16* xm, const int* lens) {
  const int idx = blockIdx.x * 256 + threadIdx.x;  // 16384*256
  const int row = idx >> 8;
  const int c4 = (idx & 255) * 4;
  const int xoff = (row & 8192) ? 0 : 1024;
  const bool live = (row & 511) < lens[(row >> 9) & 15];
  float4 v = {0.f, 0.f, 0.f, 0.f};
  if (live) v = *(const float4*)(inputs + (long)(row & 8191) * 2048 + xoff + c4);
  ushort4 o;
  o.x = f2b(v.x); o.y = f2b(v.y); o.z = f2b(v.z); o.w = f2b(v.w);
  *(ushort4*)(xm + (long)row * 1024 + c4) = o;
}

__global__ void zerok(u16* p) { p[blockIdx.x * 256 + threadIdx.x] = 0; }

extern "C" void kernel_launch(void* const* d_in, const int* in_sizes, int n_in,
                              void* d_out, int out_size, void* d_ws, size_t ws_size,
                              hipStream_t stream) {
  const float* inputs = (const float*)d_in[0];
  const float* wq = (const float*)d_in[1];
  const float* bq = (const float*)d_in[2];
  const float* wk = (const float*)d_in[3];
  const float* bk = (const float*)d_in[4];
  const float* wv = (const float*)d_in[5];
  const float* bv = (const float*)d_in[6];
  const float* gamma = (const float*)d_in[7];
  const float* w_fcf = (const float*)d_in[8];
  const float* b_fcf = (const float*)d_in[9];
  const float* w_fc1f = (const float*)d_in[10];
  const float* b_fc1f = (const float*)d_in[11];
  const float* w_fcr = (const float*)d_in[12];
  const float* b_fcr = (const float*)d_in[13];
  const float* w_fc1r = (const float*)d_in[14];
  const float* b_fc1r = (const float*)d_in[15];
  const int* lens = (const int*)d_in[16];
  float* out = (float*)d_out;

  char* ws = (char*)d_ws;
  size_t off = 0;
  auto alloc = [&](size_t n) {
    char* p = ws + off;
    off += (n + 255) & ~(size_t)255;
    return p;
  };

  // Live-set peak (conv): wt_all + xm + qb + kb + vb = 153.1 MB.
  // Aliases: attn->wt_all (post-conv); scores fp32->xm (post-conv);
  // w1b/w2b->xm region (post-softmax); abuf->qb; hbuf->kb.
  u16* wt_all = (u16*)alloc(3072l * 3072 * 2);
  u16* zpage = (u16*)alloc(4096);
  u16* xm = (u16*)alloc(16384l * 1024 * 2);
  u16* qb = (u16*)alloc(16384l * 1024 * 2);
  u16* kb = (u16*)alloc(16384l * 1024 * 2);
  u16* vb = (u16*)alloc(32l * 1024 * 512 * 2);
  u16* attn = wt_all;
  float* scores = (float*)xm;
  u16* w1b = (u16*)xm;                    // after softmax (scores dead)
  u16* w2b = w1b + 2l * 1024 * 1024;
  u16* abuf = qb;
  u16* hbuf = kb;

  zerok<<<8, 256, 0, stream>>>(zpage);
  convw_k<<<4096, 256, 0, stream>>>(wq, wt_all);
  convw_k<<<4096, 256, 0, stream>>>(wk, wt_all + 1024l * 3072);
  convw_k<<<4096, 256, 0, stream>>>(wv, wt_all + 2048l * 3072);
  xmk<<<16384, 256, 0, stream>>>(inputs, xm, lens);

  // fused q|k|v conv: M=16384, N=3072, K=3072 -> 768 blocks (3 full rounds)
  {
    G2 g{};
    g.A = xm; g.Bt = wt_all; g.zpage = zpage; g.K = 3072;
    g.out = qb; g.out2 = kb; g.out3 = vb;
    g.bias = bq; g.bias2 = bk; g.bias3 = bv;
    gemm256_k<0><<<768, 512, 0, stream>>>(g);
  }

  // scores, both halves batched (z = half*16 + b); scores fp32 aliases xm
  {
    GP g{};
    g.A = qb; g.Bt = kb; g.lda = 1024; g.ldb = 1024; g.K = 1024;
    g.sAz = 512l * 1024; g.sBz = 512l * 1024; g.out = scores;
    gemm_k<OP_SCORES><<<dim3(4, 4, 32), 256, 0, stream>>>(g);
  }
  softmax_k<<<4096, 256, 0, stream>>>(scores, attn, lens);

  // head weights -> bf16 into the (now dead) scores region
  castk<<<4096, 256, 0, stream>>>(w_fcf, w1b, 1024 * 1024);
  castk<<<4096, 256, 0, stream>>>(w_fcr, w1b + 1024l * 1024, 1024 * 1024);
  castk<<<512, 256, 0, stream>>>(w_fc1f, w2b, 128 * 1024);
  castk<<<512, 256, 0, stream>>>(w_fc1r, w2b + 128l * 1024, 128 * 1024);

  // PV: a = mask ? gamma*(attn.vT)+x : x  (z = half*16+b)
  {
    GP g{};
    g.A = attn; g.Bt = vb; g.lda = 512; g.ldb = 512; g.K = 512;
    g.sAz = 512l * 512; g.sBz = 1024l * 512;
    g.out = abuf; g.gamma = gamma; g.x_full = inputs; g.lens = lens;
    gemm_k<OP_PV><<<dim3(8, 4, 32), 256, 0, stream>>>(g);
  }

  // head1: M=16384, N=1024, K=1024 -> 256 blocks (1 full round)
  {
    G2 h{};
    h.A = abuf; h.Bt = w1b; h.Bt2 = w1b + 1024l * 1024; h.K = 1024;
    h.out = hbuf; h.bias = b_fcf; h.bias2 = b_fcr;
    gemm256_k<1><<<256, 512, 0, stream>>>(h);
  }

  // head2 -> strided concat store into d_out
  {
    GP g{};
    g.A = hbuf; g.Bt = w2b; g.lda = 1024; g.ldb = 1024; g.K = 1024;
    g.sAz = 8192l * 1024; g.sBz = 128l * 1024;
    g.out = out; g.bias = b_fc1f; g.bias2 = b_fc1r;
    gemm_k<OP_HEAD2><<<dim3(1, 64, 2), 256, 0, stream>>>(g);
  }
}